// Round 3
// baseline (334.079 us; speedup 1.0000x reference)
//
#include <hip/hip_runtime.h>
#include <hip/hip_bf16.h>

typedef short bf16x8 __attribute__((ext_vector_type(8)));
typedef float f32x16 __attribute__((ext_vector_type(16)));
typedef int   i32x4  __attribute__((ext_vector_type(4)));

#define INV_SQRT165 0.07784989441615349f
#define FINAL_SCALE 0.0032113081446662823f   /* sqrt(165)/4000 */
#define ZERO16 ((f32x16){0.f,0.f,0.f,0.f,0.f,0.f,0.f,0.f,0.f,0.f,0.f,0.f,0.f,0.f,0.f,0.f})

__device__ __forceinline__ unsigned short f2bf(float f) {
  unsigned int u = __builtin_bit_cast(unsigned int, f);
  unsigned int r = (u + 0x7FFFu + ((u >> 16) & 1u)) >> 16;
  return (unsigned short)r;
}
__device__ __forceinline__ unsigned int pack_bf2(float lo, float hi) {
  return ((unsigned int)f2bf(hi) << 16) | (unsigned int)f2bf(lo);
}

__device__ __forceinline__ void gl_lds16(const void* g, void* l) {
  __builtin_amdgcn_global_load_lds(
      (const __attribute__((address_space(1))) unsigned int*)(unsigned long long)g,
      (__attribute__((address_space(3))) unsigned int*)(unsigned int)(unsigned long long)l,
      16, 0, 0);
}

// i < 165 -> level lv (d=2lv+1), rel = i - lv^2... (block offset), quotient jj = rel/d, mm = rel%d
__device__ __forceinline__ void decode_i(int i, int& lv, int& rel) {
  if (i < 1)       { lv = 0; rel = i; }
  else if (i < 10) { lv = 1; rel = i - 1; }
  else if (i < 35) { lv = 2; rel = i - 10; }
  else if (i < 84) { lv = 3; rel = i - 35; }
  else             { lv = 4; rel = i - 84; }
}
__device__ __forceinline__ int divq(int rel, int lv) {   // rel / (2lv+1), rel < 81
  const int mag[5] = {32768, 10923, 6554, 4682, 3641};
  return (rel * mag[lv]) >> 15;
}

// ---------------- pre-pass ----------------

// blocks 0-1: psi1 (400 elems); blocks 2-12: psi2 (2640 elems)
__global__ void psi_k(const float* __restrict__ Y, const float* __restrict__ w_s2,
                      const float* __restrict__ Dk, const float* __restrict__ w_so3,
                      float* __restrict__ psi1, float* __restrict__ psi2) {
  int bx = blockIdx.x;
  if (bx < 2) {
    int t = bx * 256 + threadIdx.x;
    if (t >= 400) return;
    int y = t / 25, i = t % 25;
    float s = 0.f;
    for (int n = 0; n < 48; n++) s += Y[n * 25 + i] * w_s2[y * 48 + n];
    psi1[t] = s * 0.14433756729740643f;
  } else {
    int t = (bx - 2) * 256 + threadIdx.x;
    if (t >= 2640) return;
    int ch = t / 165, i = t % 165;
    float s = 0.f;
    for (int n = 0; n < 192; n++) s += Dk[n * 165 + i] * w_so3[ch * 192 + n];
    psi2[t] = s * 0.07216878364870323f;
  }
}

// One block per g-chunk ci (126): coalesced-load Da[g0..g0+31][0..164] into LDS,
// emit d1pre (A-frag layout) and d2pre (B-frag layout).
__global__ __launch_bounds__(256) void dapre_k(const float* __restrict__ Da,
                                               unsigned short* __restrict__ d1pre,
                                               unsigned short* __restrict__ d2pre) {
  __shared__ __align__(16) unsigned short lds[32 * 200];
  const int tid = threadIdx.x;
  const int ci = blockIdx.x, g0 = ci * 32;
  for (int e = tid; e < 6400; e += 256) lds[e] = 0;
  __syncthreads();
  int rows = 4000 - g0; if (rows > 32) rows = 32; if (rows < 0) rows = 0;
  int ne = rows * 165;
  for (int e = tid; e < ne; e += 256) {
    int gl_ = e / 165, k = e - gl_ * 165;
    lds[gl_ * 200 + k] = f2bf(Da[g0 * 165 + e]);
  }
  __syncthreads();
  const int l = tid & 63, hl = l >> 5, ln = l & 31;
#pragma unroll
  for (int it = 0; it < 3; it++) {
    int kf = it * 4 + (tid >> 6);
    i32x4 v = *(const i32x4*)(&lds[ln * 200 + kf * 16 + hl * 8]);
    *(i32x4*)(d1pre + ci * 6144 + kf * 512 + l * 8) = v;
  }
#pragma unroll
  for (int it = 0; it < 3; it++) {
    int tt = it * 4 + (tid >> 6);
    int nf = tt >> 1, gk = tt & 1;
    unsigned short v[8];
#pragma unroll
    for (int j = 0; j < 8; j++)
      v[j] = lds[(gk * 16 + hl * 8 + j) * 200 + nf * 32 + ln];
    *(i32x4*)(d2pre + ci * 6144 + tt * 512 + l * 8) = *(i32x4*)v;
  }
}

// One block per 64-col tile of eval_wigners: coalesced rows -> LDS -> B-frag layout.
__global__ __launch_bounds__(256) void ewpre_k(const float* __restrict__ ew,
                                               unsigned short* __restrict__ ewpre) {
  __shared__ __align__(16) unsigned short lds[192 * 72];
  const int tid = threadIdx.x;
  const int n0 = blockIdx.x * 64;
  for (int e = tid; e < 13824; e += 256) lds[e] = 0;
  __syncthreads();
  for (int e = tid; e < 10560; e += 256) {          // 165 rows x 64 cols
    int k = e >> 6, n = e & 63;
    lds[k * 72 + n] = f2bf(ew[k * 4608 + n0 + n]);
  }
  __syncthreads();
  const int l = tid & 63, hl = l >> 5, ln = l & 31;
#pragma unroll
  for (int it = 0; it < 6; it++) {
    int tb = it * 4 + (tid >> 6);
    int nt2 = tb / 12, kf = tb - nt2 * 12;
    unsigned short v[8];
#pragma unroll
    for (int j = 0; j < 8; j++)
      v[j] = lds[(kf * 16 + hl * 8 + j) * 72 + nt2 * 32 + ln];
    *(i32x4*)(ewpre + (blockIdx.x * 2 + nt2) * 6144 + kf * 512 + l * 8) = *(i32x4*)v;
  }
}

// wave per m-tile: H[m][k] = x[b, lv^2+mm] * psi1[y, lv^2+jj], A-frag layout, 16B stores
__global__ __launch_bounds__(256) void h1pre_k(const float* __restrict__ x,
                                               const float* __restrict__ psi1,
                                               unsigned short* __restrict__ h1pre) {
  const int tid = threadIdx.x;
  const int w = tid >> 6, l = tid & 63;
  const int hl = l >> 5, ln = l & 31;
  const int mt = blockIdx.x * 4 + w;
  const int m = mt * 32 + ln;
  const float* xr = x + (m >> 4) * 25;
  const float* pr = psi1 + (m & 15) * 25;
#pragma unroll
  for (int kf = 0; kf < 12; kf++) {
    unsigned short v[8];
#pragma unroll
    for (int j = 0; j < 8; j++) {
      int k = kf * 16 + hl * 8 + j;
      unsigned short o = 0;
      if (k < 165) {
        int lv, rel; decode_i(k, lv, rel);
        int d = 2 * lv + 1;
        int jj = divq(rel, lv), mm = rel - jj * d;
        int xo = lv * lv;
        o = f2bf(xr[xo + mm] * pr[xo + jj]);
      }
      v[j] = o;
    }
    *(i32x4*)(h1pre + mt * 6144 + kf * 512 + l * 8) = *(i32x4*)v;
  }
}

// ---------------- fused MLP + so3-linear ----------------
// 512 threads = 8 waves: wave w -> m-tile (w&3), chunk-half h=(w>>2).
// Iter ci (0..62): half h computes chunk 2ci+h. d1 tiles via LDS (dbuf, global_load_lds),
// d2 tiles via global (L2/L1-resident). One barrier per iter. fp32 LDS reduction epilogue.
__global__ __launch_bounds__(512, 2) void fused_mlp_k(
    const unsigned short* __restrict__ h1pre,
    const unsigned short* __restrict__ d1pre,
    const unsigned short* __restrict__ d2pre,
    const float* __restrict__ psi2,
    float* __restrict__ harm_out,
    unsigned short* __restrict__ harmbpre)
{
  __shared__ __align__(16) unsigned char smem[49152];   // 2 x 24KB d1 buffers / epilogue fp32
  const int tid = threadIdx.x;
  const int w = tid >> 6, l = tid & 63;
  const int hl = l >> 5, ln = l & 31;
  const int mt = w & 3, h = w >> 2;
  const int bx = blockIdx.x;

  bf16x8 hfr[12];
  {
    const short* hp = (const short*)h1pre + (bx * 4 + mt) * 6144 + l * 8;
#pragma unroll
    for (int kf = 0; kf < 12; kf++) hfr[kf] = *(const bf16x8*)(hp + kf * 512);
  }
  f32x16 o[6];
#pragma unroll
  for (int nf = 0; nf < 6; nf++) o[nf] = ZERO16;

  // stage iteration it (chunks 2it, 2it+1): 24 x 1KB blocks, 3 per wave
#pragma unroll
  for (int i = 0; i < 3; i++) {
    int tb = w * 3 + i;
    int cs = (tb >= 12), kfb = tb - cs * 12;
    gl_lds16(d1pre + cs * 6144 + kfb * 512 + l * 8, smem + tb * 1024);
  }

  for (int ci = 0; ci < 63; ci++) {
    __syncthreads();
    const unsigned char* cb = smem + (ci & 1) * 24576 + h * 12288;
    if (ci < 62) {
      const int nx = ci + 1;
      const unsigned char* nb = smem + (nx & 1) * 24576;
      const short* src = (const short*)d1pre + 2 * nx * 6144;
#pragma unroll
      for (int i = 0; i < 3; i++) {
        int tb = w * 3 + i;
        int cs = (tb >= 12), kfb = tb - cs * 12;
        gl_lds16(src + cs * 6144 + kfb * 512 + l * 8, (void*)(nb + tb * 1024));
      }
    }
    // GEMM2 B-frags direct from global (L2/L1)
    bf16x8 b2[12];
    {
      const short* d2p = (const short*)d2pre + (2 * ci + h) * 6144 + l * 8;
#pragma unroll
      for (int t = 0; t < 12; t++) b2[t] = *(const bf16x8*)(d2p + t * 512);
    }
    // GEMM1: S^T = Dtile . H^T (2 chains)
    f32x16 c0 = ZERO16, c1 = ZERO16;
#pragma unroll
    for (int kf = 0; kf < 12; kf += 2) {
      bf16x8 aD0 = *(const bf16x8*)(cb + kf * 1024 + l * 16);
      bf16x8 aD1 = *(const bf16x8*)(cb + (kf + 1) * 1024 + l * 16);
      c0 = __builtin_amdgcn_mfma_f32_32x32x16_bf16(aD0, hfr[kf], c0, 0, 0, 0);
      c1 = __builtin_amdgcn_mfma_f32_32x32x16_bf16(aD1, hfr[kf + 1], c1, 0, 0, 0);
    }
    // relu + scale + pack
    unsigned int dw[8];
#pragma unroll
    for (int p = 0; p < 8; p++) {
      float v0 = fmaxf((c0[2 * p]     + c1[2 * p])     * INV_SQRT165, 0.f);
      float v1 = fmaxf((c0[2 * p + 1] + c1[2 * p + 1]) * INV_SQRT165, 0.f);
      dw[p] = pack_bf2(v0, v1);
    }
    // cross-half exchange -> A-frags of S
    unsigned int r1 = __shfl_xor(hl ? dw[0] : dw[2], 32);
    unsigned int r2 = __shfl_xor(hl ? dw[1] : dw[3], 32);
    unsigned int r3 = __shfl_xor(hl ? dw[4] : dw[6], 32);
    unsigned int r4 = __shfl_xor(hl ? dw[5] : dw[7], 32);
    i32x4 a2i0, a2i1;
    if (hl == 0) {
      a2i0 = (i32x4){(int)dw[0], (int)dw[1], (int)r1, (int)r2};
      a2i1 = (i32x4){(int)dw[4], (int)dw[5], (int)r3, (int)r4};
    } else {
      a2i0 = (i32x4){(int)r1, (int)r2, (int)dw[2], (int)dw[3]};
      a2i1 = (i32x4){(int)r3, (int)r4, (int)dw[6], (int)dw[7]};
    }
    bf16x8 a2_0 = __builtin_bit_cast(bf16x8, a2i0);
    bf16x8 a2_1 = __builtin_bit_cast(bf16x8, a2i1);
    // GEMM2
#pragma unroll
    for (int gk = 0; gk < 2; gk++) {
      bf16x8 a2 = gk ? a2_1 : a2_0;
#pragma unroll
      for (int nf = 0; nf < 6; nf++)
        o[nf] = __builtin_amdgcn_mfma_f32_32x32x16_bf16(a2, b2[nf * 2 + gk], o[nf], 0, 0, 0);
    }
  }

  // ---------------- epilogue: cross-half fp32 reduction + so3_to_so3 ----------------
  __syncthreads();
  float* ost = (float*)smem;                 // [2][32][180] fp32 per round
  for (int r = 0; r < 2; r++) {
    const int mine = ((mt >> 1) == r);
    float* reg = ost + (mt & 1) * 5760;
    if (mine && h == 0) {
#pragma unroll
      for (int nf = 0; nf < 6; nf++) {
        int n = nf * 32 + ln;
        if (n < 176) {
#pragma unroll
          for (int r16 = 0; r16 < 16; r16++) {
            int row = (r16 & 3) + 8 * (r16 >> 2) + 4 * hl;
            reg[row * 180 + n] = o[nf][r16] * FINAL_SCALE;
          }
        }
      }
    }
    __syncthreads();
    if (mine && h == 1) {
#pragma unroll
      for (int nf = 0; nf < 6; nf++) {
        int n = nf * 32 + ln;
        if (n < 176) {
#pragma unroll
          for (int r16 = 0; r16 < 16; r16++) {
            int row = (r16 & 3) + 8 * (r16 >> 2) + 4 * hl;
            reg[row * 180 + n] += o[nf][r16] * FINAL_SCALE;
          }
        }
      }
    }
    __syncthreads();
    // so3_to_so3 for the 4 batches of this round
    for (int jj = tid; jj < 768; jj += 512) {
      int e = jj / 192, i = jj - e * 192;
      int bb = bx * 8 + r * 4 + e;
      unsigned short* hb = harmbpre + (((bb >> 5) * 12 + (i >> 4)) << 9)
                         + ((i >> 3) & 1) * 256 + (bb & 31) * 8 + (i & 7);
      if (i < 165) {
        const float* row0 = ost + (e >> 1) * 5760 + (e & 1) * 2880;
        int lv, rel; decode_i(i, lv, rel);
        int d = 2 * lv + 1;
        int off = i - rel;
        int v = divq(rel, lv), m = rel - v * d;
        float s = 0.f;
        for (int ch = 0; ch < 16; ch++) {
          const float* rw = row0 + ch * 180 + off;
          const float* p2 = psi2 + ch * 165 + off;
          for (int u = 0; u < d; u++) s += rw[u * d + m] * p2[u * d + v];
        }
        s *= 0.25f * rsqrtf((float)d);
        harm_out[bb * 165 + i] = s;
        *hb = f2bf(s);
      } else {
        *hb = 0;
      }
    }
    __syncthreads();
  }
}

// ---------------- eval GEMM: logits = harm . ew  (2048 x 4608, K=192) ----------------
__global__ __launch_bounds__(256) void eval_k(
    const unsigned short* __restrict__ harmbpre,
    const unsigned short* __restrict__ ewpre,
    float* __restrict__ logits)
{
  const int tid = threadIdx.x;
  const int w = tid >> 6, l = tid & 63;
  const int hl = l >> 5, ln = l & 31;
  const int mt = blockIdx.y * 4 + w;
  const int n0 = blockIdx.x * 192;

  bf16x8 a[12];
  const short* ap = (const short*)harmbpre + mt * 6144 + l * 8;
#pragma unroll
  for (int kf = 0; kf < 12; kf++) a[kf] = *(const bf16x8*)(ap + kf * 512);

  const short* bp = (const short*)ewpre + (blockIdx.x * 6) * 6144 + l * 8;
#pragma unroll
  for (int nf = 0; nf < 6; nf++) {
    f32x16 acc = ZERO16;
    const short* bpn = bp + nf * 6144;
#pragma unroll
    for (int kf = 0; kf < 12; kf++) {
      bf16x8 b = *(const bf16x8*)(bpn + kf * 512);
      acc = __builtin_amdgcn_mfma_f32_32x32x16_bf16(a[kf], b, acc, 0, 0, 0);
    }
    const int col = n0 + nf * 32 + ln;
#pragma unroll
    for (int r = 0; r < 16; r++) {
      int row = (r & 3) + 8 * (r >> 2) + 4 * hl;
      logits[(mt * 32 + row) * 4608 + col] = acc[r];
    }
  }
}

// ---------------- fifth prob from row-0 logits ----------------
__global__ __launch_bounds__(256) void fifth_k(const float* __restrict__ logit0,
                                               float* __restrict__ fifth) {
  __shared__ float buf[4608];
  __shared__ float sm[4], ss[4];
  __shared__ float wv[4]; __shared__ int wi[4];
  __shared__ float gbest;
  const int tid = threadIdx.x;
  const int l = tid & 63, w = tid >> 6;
  float v[18];
  float mx = -3.4e38f;
#pragma unroll
  for (int i = 0; i < 18; i++) {
    v[i] = logit0[i * 256 + tid];
    buf[i * 256 + tid] = v[i];
    mx = fmaxf(mx, v[i]);
  }
#pragma unroll
  for (int off = 32; off >= 1; off >>= 1) mx = fmaxf(mx, __shfl_xor(mx, off));
  if (l == 0) sm[w] = mx;
  __syncthreads();
  mx = fmaxf(fmaxf(sm[0], sm[1]), fmaxf(sm[2], sm[3]));
  float s = 0.f;
#pragma unroll
  for (int i = 0; i < 18; i++) { v[i] = __expf(v[i] - mx); s += v[i]; }
#pragma unroll
  for (int off = 32; off >= 1; off >>= 1) s += __shfl_xor(s, off);
  if (l == 0) ss[w] = s;
  __syncthreads();
  s = ss[0] + ss[1] + ss[2] + ss[3];
  float inv = 1.f / s;

  float ff = 0.f;
  for (int it = 0; it < 5; it++) {
    float bm = -3.4e38f; int bi = 0;
    for (int i = tid; i < 4608; i += 256) {
      float xx = buf[i];
      if (xx > bm) { bm = xx; bi = i; }
    }
    for (int off = 32; off >= 1; off >>= 1) {
      float ov = __shfl_xor(bm, off); int oi = __shfl_xor(bi, off);
      if (ov > bm) { bm = ov; bi = oi; }
    }
    if (l == 0) { wv[w] = bm; wi[w] = bi; }
    __syncthreads();
    if (tid == 0) {
      float B = wv[0]; int I = wi[0];
      for (int k = 1; k < 4; k++) if (wv[k] > B) { B = wv[k]; I = wi[k]; }
      gbest = B;
      buf[I] = -3.4e38f;
    }
    __syncthreads();
    ff = gbest;
    __syncthreads();
  }
  if (tid == 0) *fifth = __expf(ff - mx) * inv;
}

// ---------------- fused softmax + threshold ----------------
__global__ __launch_bounds__(256) void smthresh_k(float* __restrict__ probs,
                                                  const float* __restrict__ fifth) {
  float* p = probs + (size_t)blockIdx.x * 4608;
  const int tid = threadIdx.x;
  const int l = tid & 63, w = tid >> 6;
  __shared__ float sm[4], ss[4];
  float v[18];
  float mx = -3.4e38f;
#pragma unroll
  for (int i = 0; i < 18; i++) { v[i] = p[i * 256 + tid]; mx = fmaxf(mx, v[i]); }
#pragma unroll
  for (int off = 32; off >= 1; off >>= 1) mx = fmaxf(mx, __shfl_xor(mx, off));
  if (l == 0) sm[w] = mx;
  __syncthreads();
  mx = fmaxf(fmaxf(sm[0], sm[1]), fmaxf(sm[2], sm[3]));
  float s = 0.f;
#pragma unroll
  for (int i = 0; i < 18; i++) { v[i] = __expf(v[i] - mx); s += v[i]; }
#pragma unroll
  for (int off = 32; off >= 1; off >>= 1) s += __shfl_xor(s, off);
  if (l == 0) ss[w] = s;
  __syncthreads();
  s = ss[0] + ss[1] + ss[2] + ss[3];
  float inv = 1.f / s;
  float t = *fifth;
#pragma unroll
  for (int i = 0; i < 18; i++) {
    float pv = v[i] * inv;
    p[i * 256 + tid] = (pv < t) ? 0.f : pv;
  }
}

extern "C" void kernel_launch(void* const* d_in, const int* in_sizes, int n_in,
                              void* d_out, int out_size, void* d_ws, size_t ws_size,
                              hipStream_t stream) {
  const float* x     = (const float*)d_in[0];
  const float* w_s2  = (const float*)d_in[1];
  const float* Y     = (const float*)d_in[2];
  const float* w_so3 = (const float*)d_in[3];
  const float* Dk    = (const float*)d_in[4];
  const float* Da    = (const float*)d_in[5];
  const float* ew    = (const float*)d_in[6];

  float* out = (float*)d_out;
  float* harm_out = out;                 // 2048*165
  float* probs    = out + 337920;        // 2048*4608 (logits first)

  char* ws = (char*)d_ws;
  float* psi1  = (float*)(ws + 0);                         // 1,600 B
  float* psi2  = (float*)(ws + 1600);                      // 10,560 B
  float* fifth = (float*)(ws + 12160);                     // 4 B
  unsigned short* h1pre    = (unsigned short*)(ws + 12224);      // 12,582,912 B
  unsigned short* d1pre    = (unsigned short*)(ws + 12595136);   // 1,548,288 B
  unsigned short* d2pre    = (unsigned short*)(ws + 14143424);   // 1,548,288 B
  unsigned short* ewpre    = (unsigned short*)(ws + 15691712);   // 1,769,472 B
  unsigned short* harmbpre = (unsigned short*)(ws + 17461184);   // 786,432 B

  psi_k   <<<13,  256, 0, stream>>>(Y, w_s2, Dk, w_so3, psi1, psi2);
  dapre_k <<<126, 256, 0, stream>>>(Da, d1pre, d2pre);
  ewpre_k <<<72,  256, 0, stream>>>(ew, ewpre);
  h1pre_k <<<256, 256, 0, stream>>>(x, psi1, h1pre);
  fused_mlp_k<<<256, 512, 0, stream>>>(h1pre, d1pre, d2pre, psi2, harm_out, harmbpre);
  eval_k<<<dim3(24, 16), 256, 0, stream>>>(harmbpre, ewpre, probs);
  fifth_k<<<1, 256, 0, stream>>>(probs, fifth);
  smthresh_k<<<2048, 256, 0, stream>>>(probs, fifth);
}

// Round 4
// 265.818 us; speedup vs baseline: 1.2568x; 1.2568x over previous
//
#include <hip/hip_runtime.h>

typedef short bf16x8 __attribute__((ext_vector_type(8)));
typedef float f32x16 __attribute__((ext_vector_type(16)));
typedef int   i32x4  __attribute__((ext_vector_type(4)));

#define INV_SQRT165 0.07784989441615349f
#define FINAL_SCALE 0.0032113081446662823f   /* sqrt(165)/4000 */
#define ZERO16 ((f32x16){0.f,0.f,0.f,0.f,0.f,0.f,0.f,0.f,0.f,0.f,0.f,0.f,0.f,0.f,0.f,0.f})

__device__ __forceinline__ unsigned short f2bf(float f) {
  unsigned int u = __builtin_bit_cast(unsigned int, f);
  unsigned int r = (u + 0x7FFFu + ((u >> 16) & 1u)) >> 16;
  return (unsigned short)r;
}
__device__ __forceinline__ float bf2f(unsigned short h) {
  unsigned int u = ((unsigned int)h) << 16;
  return __builtin_bit_cast(float, u);
}
__device__ __forceinline__ unsigned int pack_bf2(float lo, float hi) {
  return ((unsigned int)f2bf(hi) << 16) | (unsigned int)f2bf(lo);
}

__device__ __forceinline__ void gl_lds16(const void* g, void* l) {
  __builtin_amdgcn_global_load_lds(
      (const __attribute__((address_space(1))) unsigned int*)(unsigned long long)g,
      (__attribute__((address_space(3))) unsigned int*)(unsigned int)(unsigned long long)l,
      16, 0, 0);
}

__device__ __forceinline__ void decode_i(int i, int& lv, int& rel) {
  if (i < 1)       { lv = 0; rel = i; }
  else if (i < 10) { lv = 1; rel = i - 1; }
  else if (i < 35) { lv = 2; rel = i - 10; }
  else if (i < 84) { lv = 3; rel = i - 35; }
  else             { lv = 4; rel = i - 84; }
}
__device__ __forceinline__ int divq(int rel, int lv) {   // rel / (2lv+1), rel < 81
  const int mag[5] = {32768, 10923, 6554, 4682, 3641};
  return (rel * mag[lv]) >> 15;
}

// ---------------- pre-pass ----------------

// blocks 0-1: psi1 (400 elems); blocks 2-12: psi2 (2640 elems)
__global__ void psi_k(const float* __restrict__ Y, const float* __restrict__ w_s2,
                      const float* __restrict__ Dk, const float* __restrict__ w_so3,
                      float* __restrict__ psi1, float* __restrict__ psi2) {
  int bx = blockIdx.x;
  if (bx < 2) {
    int t = bx * 256 + threadIdx.x;
    if (t >= 400) return;
    int y = t / 25, i = t % 25;
    float s = 0.f;
    for (int n = 0; n < 48; n++) s += Y[n * 25 + i] * w_s2[y * 48 + n];
    psi1[t] = s * 0.14433756729740643f;
  } else {
    int t = (bx - 2) * 256 + threadIdx.x;
    if (t >= 2640) return;
    int ch = t / 165, i = t % 165;
    float s = 0.f;
    for (int n = 0; n < 192; n++) s += Dk[n * 165 + i] * w_so3[ch * 192 + n];
    psi2[t] = s * 0.07216878364870323f;
  }
}

// blocks 0..125: D_act -> d1pre (A-frag) + d2pre (B-frag).  blocks 126..197: ew -> ewpre.
__global__ __launch_bounds__(256) void prep_k(const float* __restrict__ Da,
                                              const float* __restrict__ ew,
                                              unsigned short* __restrict__ d1pre,
                                              unsigned short* __restrict__ d2pre,
                                              unsigned short* __restrict__ ewpre) {
  __shared__ __align__(16) unsigned short lds[13824];
  const int tid = threadIdx.x;
  const int l = tid & 63, hl = l >> 5, ln = l & 31;
  if (blockIdx.x < 126) {
    const int ci = blockIdx.x, g0 = ci * 32;
    for (int e = tid; e < 6400; e += 256) lds[e] = 0;
    __syncthreads();
    int rows = 4000 - g0; if (rows > 32) rows = 32; if (rows < 0) rows = 0;
    int ne = rows * 165;
    for (int e = tid; e < ne; e += 256) {
      int gl_ = e / 165, k = e - gl_ * 165;
      lds[gl_ * 200 + k] = f2bf(Da[g0 * 165 + e]);
    }
    __syncthreads();
#pragma unroll
    for (int it = 0; it < 3; it++) {
      int kf = it * 4 + (tid >> 6);
      i32x4 v = *(const i32x4*)(&lds[ln * 200 + kf * 16 + hl * 8]);
      *(i32x4*)(d1pre + ci * 6144 + kf * 512 + l * 8) = v;
    }
#pragma unroll
    for (int it = 0; it < 3; it++) {
      int tt = it * 4 + (tid >> 6);
      int nf = tt >> 1, gk = tt & 1;
      unsigned short v[8];
#pragma unroll
      for (int j = 0; j < 8; j++)
        v[j] = lds[(gk * 16 + hl * 8 + j) * 200 + nf * 32 + ln];
      *(i32x4*)(d2pre + ci * 6144 + tt * 512 + l * 8) = *(i32x4*)v;
    }
  } else {
    const int bx2 = blockIdx.x - 126;
    const int n0 = bx2 * 64;
    for (int e = tid; e < 13824; e += 256) lds[e] = 0;
    __syncthreads();
    for (int e = tid; e < 10560; e += 256) {          // 165 rows x 64 cols
      int k = e >> 6, n = e & 63;
      lds[k * 72 + n] = f2bf(ew[k * 4608 + n0 + n]);
    }
    __syncthreads();
#pragma unroll
    for (int it = 0; it < 6; it++) {
      int tb = it * 4 + (tid >> 6);
      int nt2 = tb / 12, kf = tb - nt2 * 12;
      unsigned short v[8];
#pragma unroll
      for (int j = 0; j < 8; j++)
        v[j] = lds[(kf * 16 + hl * 8 + j) * 72 + nt2 * 32 + ln];
      *(i32x4*)(ewpre + (bx2 * 2 + nt2) * 6144 + kf * 512 + l * 8) = *(i32x4*)v;
    }
  }
}

// ---------------- fused MLP, g-split halves ----------------
// Grid 512: h = bx&1 (g-half), mg = bx>>1. Block = 4 waves x M=32. 63 chunks of 32 g.
// 2 blocks/CU (48 KB LDS each) -> independent barrier domains interleave on the SIMDs.
// Emits bf16 partial O in frag layout: part[(mt*2+h)][nf][l][r16].
__global__ __launch_bounds__(256, 2) void fused_mlp_k(
    const float* __restrict__ x,
    const float* __restrict__ psi1,
    const unsigned short* __restrict__ d1pre,
    const unsigned short* __restrict__ d2pre,
    unsigned short* __restrict__ part)
{
  __shared__ __align__(16) unsigned char smem[49152];   // 2 x 24KB tile buffers
  const int tid = threadIdx.x;
  const int w = tid >> 6, l = tid & 63;
  const int hl = l >> 5, ln = l & 31;
  const int h = blockIdx.x & 1, mg = blockIdx.x >> 1;
  const int mt = mg * 4 + w;
  const int c0 = h * 63;

  // H fragments computed in-register from x (x) psi1 (no HBM round-trip)
  bf16x8 hfr[12];
  {
    const int m = mt * 32 + ln;
    const float* xr = x + (m >> 4) * 25;
    const float* pr = psi1 + (m & 15) * 25;
#pragma unroll
    for (int kf = 0; kf < 12; kf++) {
      unsigned short v[8];
#pragma unroll
      for (int j = 0; j < 8; j++) {
        int k = kf * 16 + hl * 8 + j;
        unsigned short ov = 0;
        if (k < 165) {
          int lv, rel; decode_i(k, lv, rel);
          int d = 2 * lv + 1;
          int jj = divq(rel, lv), mm = rel - jj * d;
          int xo = lv * lv;
          ov = f2bf(xr[xo + mm] * pr[xo + jj]);
        }
        v[j] = ov;
      }
      hfr[kf] = *(bf16x8*)v;
    }
  }

  f32x16 o[6];
#pragma unroll
  for (int nf = 0; nf < 6; nf++) o[nf] = ZERO16;

  // prologue: prefetch chunk c0 -> buffer 0 (24 x 1KB, 6 per wave)
#pragma unroll
  for (int i = 0; i < 6; i++) {
    int tb = w * 6 + i;
    int cs = (tb >= 12), kfb = tb - cs * 12;
    const unsigned short* g = (cs ? d2pre : d1pre) + c0 * 6144 + kfb * 512 + l * 8;
    gl_lds16(g, smem + tb * 1024);
  }

  for (int ci = 0; ci < 63; ci++) {
    __syncthreads();
    const unsigned char* cb = smem + (ci & 1) * 24576;
    if (ci < 62) {
      const unsigned char* nb = smem + ((ci + 1) & 1) * 24576;
      const int c = c0 + ci + 1;
#pragma unroll
      for (int i = 0; i < 6; i++) {
        int tb = w * 6 + i;
        int cs = (tb >= 12), kfb = tb - cs * 12;
        const unsigned short* g = (cs ? d2pre : d1pre) + c * 6144 + kfb * 512 + l * 8;
        gl_lds16(g, (void*)(nb + tb * 1024));
      }
    }
    // GEMM1: S^T = Dtile . H^T (2 chains)
    f32x16 c0a = ZERO16, c1a = ZERO16;
#pragma unroll
    for (int kf = 0; kf < 12; kf += 2) {
      bf16x8 aD0 = *(const bf16x8*)(cb + kf * 1024 + l * 16);
      bf16x8 aD1 = *(const bf16x8*)(cb + (kf + 1) * 1024 + l * 16);
      c0a = __builtin_amdgcn_mfma_f32_32x32x16_bf16(aD0, hfr[kf], c0a, 0, 0, 0);
      c1a = __builtin_amdgcn_mfma_f32_32x32x16_bf16(aD1, hfr[kf + 1], c1a, 0, 0, 0);
    }
    // relu + scale + pack
    unsigned int dw[8];
#pragma unroll
    for (int p = 0; p < 8; p++) {
      float v0 = fmaxf((c0a[2 * p]     + c1a[2 * p])     * INV_SQRT165, 0.f);
      float v1 = fmaxf((c0a[2 * p + 1] + c1a[2 * p + 1]) * INV_SQRT165, 0.f);
      dw[p] = pack_bf2(v0, v1);
    }
    // cross-half exchange -> A-frags of S
    unsigned int r1 = __shfl_xor(hl ? dw[0] : dw[2], 32);
    unsigned int r2 = __shfl_xor(hl ? dw[1] : dw[3], 32);
    unsigned int r3 = __shfl_xor(hl ? dw[4] : dw[6], 32);
    unsigned int r4 = __shfl_xor(hl ? dw[5] : dw[7], 32);
    i32x4 a2i0, a2i1;
    if (hl == 0) {
      a2i0 = (i32x4){(int)dw[0], (int)dw[1], (int)r1, (int)r2};
      a2i1 = (i32x4){(int)dw[4], (int)dw[5], (int)r3, (int)r4};
    } else {
      a2i0 = (i32x4){(int)r1, (int)r2, (int)dw[2], (int)dw[3]};
      a2i1 = (i32x4){(int)r3, (int)r4, (int)dw[6], (int)dw[7]};
    }
    bf16x8 a2_0 = __builtin_bit_cast(bf16x8, a2i0);
    bf16x8 a2_1 = __builtin_bit_cast(bf16x8, a2i1);
    // GEMM2 (B from LDS)
    const unsigned char* d2b = cb + 12288;
#pragma unroll
    for (int gk = 0; gk < 2; gk++) {
      bf16x8 a2 = gk ? a2_1 : a2_0;
#pragma unroll
      for (int nf = 0; nf < 6; nf++) {
        bf16x8 b2 = *(const bf16x8*)(d2b + (nf * 2 + gk) * 1024 + l * 16);
        o[nf] = __builtin_amdgcn_mfma_f32_32x32x16_bf16(a2, b2, o[nf], 0, 0, 0);
      }
    }
  }

  // store bf16 partials, coalesced (lane-contiguous 32 B per nf)
  unsigned short* pp = part + (size_t)(mt * 2 + h) * 6144;
#pragma unroll
  for (int nf = 0; nf < 6; nf++) {
    unsigned int dwv[8];
#pragma unroll
    for (int p = 0; p < 8; p++) dwv[p] = pack_bf2(o[nf][2 * p], o[nf][2 * p + 1]);
    *(i32x4*)(pp + nf * 1024 + l * 16)     = *(i32x4*)(dwv);
    *(i32x4*)(pp + nf * 1024 + l * 16 + 8) = *(i32x4*)(dwv + 4);
  }
}

// ---------------- partial reduce + so3_to_so3 ----------------
// One block per m-tile (1024): sum two halves, scale, stage O[32][180] in LDS, contract.
__global__ __launch_bounds__(256) void so3_k(const unsigned short* __restrict__ part,
                                             const float* __restrict__ psi2,
                                             float* __restrict__ harm_out,
                                             unsigned short* __restrict__ harmbpre) {
  __shared__ float lds[32 * 180];
  const int tid = threadIdx.x;
  const int mt = blockIdx.x;
  const unsigned int* p0 = (const unsigned int*)(part + (size_t)(mt * 2) * 6144);
  const unsigned int* p1 = (const unsigned int*)(part + (size_t)(mt * 2 + 1) * 6144);
#pragma unroll
  for (int k = 0; k < 12; k++) {
    int di = k * 256 + tid;
    unsigned int u0 = p0[di], u1 = p1[di];
    int e = di * 2;
    int nf = e >> 10, r = e & 1023, lL = r >> 4, r16 = r & 15;
    int n = nf * 32 + (lL & 31);
    int rowbase = 4 * (lL >> 5);
    if (n < 176) {
      float s0 = bf2f((unsigned short)(u0 & 0xFFFF)) + bf2f((unsigned short)(u1 & 0xFFFF));
      float s1 = bf2f((unsigned short)(u0 >> 16))    + bf2f((unsigned short)(u1 >> 16));
      int row0 = (r16 & 3) + 8 * (r16 >> 2) + rowbase;
      int r17 = r16 + 1;
      int row1 = (r17 & 3) + 8 * (r17 >> 2) + rowbase;
      lds[row0 * 180 + n] = s0 * FINAL_SCALE;
      lds[row1 * 180 + n] = s1 * FINAL_SCALE;
    }
  }
  __syncthreads();
  for (int jj = tid; jj < 384; jj += 256) {
    int e = jj / 192, i = jj - e * 192;
    int bb = mt * 2 + e;
    unsigned short* hb = harmbpre + (((bb >> 5) * 12 + (i >> 4)) << 9)
                       + ((i >> 3) & 1) * 256 + (bb & 31) * 8 + (i & 7);
    if (i < 165) {
      const float* row0 = lds + e * 16 * 180;
      int lv, rel; decode_i(i, lv, rel);
      int d = 2 * lv + 1;
      int off = i - rel;
      int v = divq(rel, lv), m = rel - v * d;
      float s = 0.f;
      for (int ch = 0; ch < 16; ch++) {
        const float* rw = row0 + ch * 180 + off;
        const float* p2 = psi2 + ch * 165 + off;
        for (int u = 0; u < d; u++) s += rw[u * d + m] * p2[u * d + v];
      }
      s *= 0.25f * rsqrtf((float)d);
      harm_out[bb * 165 + i] = s;
      *hb = f2bf(s);
    } else {
      *hb = 0;
    }
  }
}

// ---------------- eval GEMM: logits = harm . ew  (2048 x 4608, K=192) ----------------
__global__ __launch_bounds__(256) void eval_k(
    const unsigned short* __restrict__ harmbpre,
    const unsigned short* __restrict__ ewpre,
    float* __restrict__ logits)
{
  const int tid = threadIdx.x;
  const int w = tid >> 6, l = tid & 63;
  const int hl = l >> 5, ln = l & 31;
  const int mt = blockIdx.y * 4 + w;
  const int n0 = blockIdx.x * 192;

  bf16x8 a[12];
  const short* ap = (const short*)harmbpre + mt * 6144 + l * 8;
#pragma unroll
  for (int kf = 0; kf < 12; kf++) a[kf] = *(const bf16x8*)(ap + kf * 512);

  f32x16 acc[6];
#pragma unroll
  for (int nf = 0; nf < 6; nf++) acc[nf] = ZERO16;

  const short* bp = (const short*)ewpre + (blockIdx.x * 6) * 6144 + l * 8;
  // 6 independent accumulate chains; loads stream ahead of MFMAs
#pragma unroll
  for (int kf = 0; kf < 12; kf++) {
#pragma unroll
    for (int nf = 0; nf < 6; nf++) {
      bf16x8 b = *(const bf16x8*)(bp + nf * 6144 + kf * 512);
      acc[nf] = __builtin_amdgcn_mfma_f32_32x32x16_bf16(a[kf], b, acc[nf], 0, 0, 0);
    }
  }
#pragma unroll
  for (int nf = 0; nf < 6; nf++) {
    const int col = n0 + nf * 32 + ln;
#pragma unroll
    for (int r = 0; r < 16; r++) {
      int row = (r & 3) + 8 * (r >> 2) + 4 * hl;
      logits[(mt * 32 + row) * 4608 + col] = acc[nf][r];
    }
  }
}

// ---------------- fifth prob from row-0 logits ----------------
__global__ __launch_bounds__(256) void fifth_k(const float* __restrict__ logit0,
                                               float* __restrict__ fifth) {
  __shared__ float buf[4608];
  __shared__ float sm[4], ss[4];
  __shared__ float wv[4]; __shared__ int wi[4];
  __shared__ float gbest;
  const int tid = threadIdx.x;
  const int l = tid & 63, w = tid >> 6;
  float v[18];
  float mx = -3.4e38f;
#pragma unroll
  for (int i = 0; i < 18; i++) {
    v[i] = logit0[i * 256 + tid];
    buf[i * 256 + tid] = v[i];
    mx = fmaxf(mx, v[i]);
  }
#pragma unroll
  for (int off = 32; off >= 1; off >>= 1) mx = fmaxf(mx, __shfl_xor(mx, off));
  if (l == 0) sm[w] = mx;
  __syncthreads();
  mx = fmaxf(fmaxf(sm[0], sm[1]), fmaxf(sm[2], sm[3]));
  float s = 0.f;
#pragma unroll
  for (int i = 0; i < 18; i++) { v[i] = __expf(v[i] - mx); s += v[i]; }
#pragma unroll
  for (int off = 32; off >= 1; off >>= 1) s += __shfl_xor(s, off);
  if (l == 0) ss[w] = s;
  __syncthreads();
  s = ss[0] + ss[1] + ss[2] + ss[3];
  float inv = 1.f / s;

  float ff = 0.f;
  for (int it = 0; it < 5; it++) {
    float bm = -3.4e38f; int bi = 0;
    for (int i = tid; i < 4608; i += 256) {
      float xx = buf[i];
      if (xx > bm) { bm = xx; bi = i; }
    }
    for (int off = 32; off >= 1; off >>= 1) {
      float ov = __shfl_xor(bm, off); int oi = __shfl_xor(bi, off);
      if (ov > bm) { bm = ov; bi = oi; }
    }
    if (l == 0) { wv[w] = bm; wi[w] = bi; }
    __syncthreads();
    if (tid == 0) {
      float B = wv[0]; int I = wi[0];
      for (int k = 1; k < 4; k++) if (wv[k] > B) { B = wv[k]; I = wi[k]; }
      gbest = B;
      buf[I] = -3.4e38f;
    }
    __syncthreads();
    ff = gbest;
    __syncthreads();
  }
  if (tid == 0) *fifth = __expf(ff - mx) * inv;
}

// ---------------- fused softmax + threshold ----------------
__global__ __launch_bounds__(256) void smthresh_k(float* __restrict__ probs,
                                                  const float* __restrict__ fifth) {
  float* p = probs + (size_t)blockIdx.x * 4608;
  const int tid = threadIdx.x;
  const int l = tid & 63, w = tid >> 6;
  __shared__ float sm[4], ss[4];
  float v[18];
  float mx = -3.4e38f;
#pragma unroll
  for (int i = 0; i < 18; i++) { v[i] = p[i * 256 + tid]; mx = fmaxf(mx, v[i]); }
#pragma unroll
  for (int off = 32; off >= 1; off >>= 1) mx = fmaxf(mx, __shfl_xor(mx, off));
  if (l == 0) sm[w] = mx;
  __syncthreads();
  mx = fmaxf(fmaxf(sm[0], sm[1]), fmaxf(sm[2], sm[3]));
  float s = 0.f;
#pragma unroll
  for (int i = 0; i < 18; i++) { v[i] = __expf(v[i] - mx); s += v[i]; }
#pragma unroll
  for (int off = 32; off >= 1; off >>= 1) s += __shfl_xor(s, off);
  if (l == 0) ss[w] = s;
  __syncthreads();
  s = ss[0] + ss[1] + ss[2] + ss[3];
  float inv = 1.f / s;
  float t = *fifth;
#pragma unroll
  for (int i = 0; i < 18; i++) {
    float pv = v[i] * inv;
    p[i * 256 + tid] = (pv < t) ? 0.f : pv;
  }
}

extern "C" void kernel_launch(void* const* d_in, const int* in_sizes, int n_in,
                              void* d_out, int out_size, void* d_ws, size_t ws_size,
                              hipStream_t stream) {
  const float* x     = (const float*)d_in[0];
  const float* w_s2  = (const float*)d_in[1];
  const float* Y     = (const float*)d_in[2];
  const float* w_so3 = (const float*)d_in[3];
  const float* Dk    = (const float*)d_in[4];
  const float* Da    = (const float*)d_in[5];
  const float* ew    = (const float*)d_in[6];

  float* out = (float*)d_out;
  float* harm_out = out;                 // 2048*165
  float* probs    = out + 337920;        // 2048*4608 (partials -> logits -> probs)
  unsigned short* part = (unsigned short*)probs;   // 25.2 MB bf16 partials (< 37.7 MB)

  char* ws = (char*)d_ws;
  float* psi1  = (float*)(ws + 0);                         // 1,600 B
  float* psi2  = (float*)(ws + 1600);                      // 10,560 B
  float* fifth = (float*)(ws + 12160);                     // 4 B
  unsigned short* d1pre    = (unsigned short*)(ws + 12224);      // 1,548,288 B
  unsigned short* d2pre    = (unsigned short*)(ws + 1560512);    // 1,548,288 B
  unsigned short* ewpre    = (unsigned short*)(ws + 3108800);    // 1,769,472 B
  unsigned short* harmbpre = (unsigned short*)(ws + 4878272);    // 786,432 B  (~5.7 MB total)

  psi_k <<<13,  256, 0, stream>>>(Y, w_s2, Dk, w_so3, psi1, psi2);
  prep_k<<<198, 256, 0, stream>>>(Da, ew, d1pre, d2pre, ewpre);
  fused_mlp_k<<<512, 256, 0, stream>>>(x, psi1, d1pre, d2pre, part);
  so3_k<<<1024, 256, 0, stream>>>(part, psi2, harm_out, harmbpre);
  eval_k<<<dim3(24, 16), 256, 0, stream>>>(harmbpre, ewpre, probs);
  fifth_k<<<1, 256, 0, stream>>>(probs, fifth);
  smthresh_k<<<2048, 256, 0, stream>>>(probs, fifth);
}

// Round 6
// 250.772 us; speedup vs baseline: 1.3322x; 1.0600x over previous
//
#include <hip/hip_runtime.h>

typedef short bf16x8 __attribute__((ext_vector_type(8)));
typedef float f32x16 __attribute__((ext_vector_type(16)));
typedef int   i32x4  __attribute__((ext_vector_type(4)));

#define INV_SQRT165 0.07784989441615349f
#define FINAL_SCALE 0.0032113081446662823f   /* sqrt(165)/4000 */
#define ZERO16 ((f32x16){0.f,0.f,0.f,0.f,0.f,0.f,0.f,0.f,0.f,0.f,0.f,0.f,0.f,0.f,0.f,0.f})

__device__ __forceinline__ unsigned short f2bf(float f) {
  unsigned int u = __builtin_bit_cast(unsigned int, f);
  unsigned int r = (u + 0x7FFFu + ((u >> 16) & 1u)) >> 16;
  return (unsigned short)r;
}
__device__ __forceinline__ float bf2f(unsigned short h) {
  unsigned int u = ((unsigned int)h) << 16;
  return __builtin_bit_cast(float, u);
}
__device__ __forceinline__ unsigned int pack_bf2(float lo, float hi) {
  return ((unsigned int)f2bf(hi) << 16) | (unsigned int)f2bf(lo);
}

__device__ __forceinline__ void gl_lds16(const void* g, void* l) {
  __builtin_amdgcn_global_load_lds(
      (const __attribute__((address_space(1))) unsigned int*)(unsigned long long)g,
      (__attribute__((address_space(3))) unsigned int*)(unsigned int)(unsigned long long)l,
      16, 0, 0);
}

__device__ __forceinline__ void decode_i(int i, int& lv, int& rel) {
  if (i < 1)       { lv = 0; rel = i; }
  else if (i < 10) { lv = 1; rel = i - 1; }
  else if (i < 35) { lv = 2; rel = i - 10; }
  else if (i < 84) { lv = 3; rel = i - 35; }
  else             { lv = 4; rel = i - 84; }
}
__device__ __forceinline__ int divq(int rel, int lv) {   // rel / (2lv+1), rel < 81
  const int mag[5] = {32768, 10923, 6554, 4682, 3641};
  return (rel * mag[lv]) >> 15;
}

// ---------------- psi1 / psi2 ----------------
__global__ void psi_k(const float* __restrict__ Y, const float* __restrict__ w_s2,
                      const float* __restrict__ Dk, const float* __restrict__ w_so3,
                      float* __restrict__ psi1, float* __restrict__ psi2) {
  int bx = blockIdx.x;
  if (bx < 2) {
    int t = bx * 256 + threadIdx.x;
    if (t >= 400) return;
    int y = t / 25, i = t % 25;
    float s = 0.f;
    for (int n = 0; n < 48; n++) s += Y[n * 25 + i] * w_s2[y * 48 + n];
    psi1[t] = s * 0.14433756729740643f;
  } else {
    int t = (bx - 2) * 256 + threadIdx.x;
    if (t >= 2640) return;
    int ch = t / 165, i = t % 165;
    float s = 0.f;
    for (int n = 0; n < 192; n++) s += Dk[n * 165 + i] * w_so3[ch * 192 + n];
    psi2[t] = s * 0.07216878364870323f;
  }
}

// ---------------- prep: E-table (psi1 folded into Da) + d2pre + ewpre ----------------
// blocks 0..127 (g-chunk ci): d2pre[ci][tt12][512] B-frags; e1pre[y][ci][kf2][512] A-frags
// blocks 128..199: ewpre (72 x 64-col tiles)
__global__ __launch_bounds__(256) void prep_k(const float* __restrict__ Da,
                                              const float* __restrict__ ew,
                                              const float* __restrict__ psi1,
                                              unsigned short* __restrict__ e1pre,
                                              unsigned short* __restrict__ d2pre,
                                              unsigned short* __restrict__ ewpre) {
  __shared__ __align__(16) unsigned short lds[13824];
  const int tid = threadIdx.x;
  const int l = tid & 63, hl = l >> 5, ln = l & 31;
  if (blockIdx.x < 128) {
    const int ci = blockIdx.x, g0 = ci * 32;
    float* psi1L = (float*)(lds + 6464);
    for (int e = tid; e < 6400; e += 256) lds[e] = 0;
    for (int e = tid; e < 400; e += 256) psi1L[e] = psi1[e];
    __syncthreads();
    int rows = 4000 - g0; if (rows > 32) rows = 32; if (rows < 0) rows = 0;
    int ne = rows * 165;
    for (int e = tid; e < ne; e += 256) {
      int gl_ = e / 165, k = e - gl_ * 165;
      lds[gl_ * 200 + k] = f2bf(Da[g0 * 165 + e]);
    }
    __syncthreads();
    // d2pre: B-frag layout of Da (n x g)
#pragma unroll
    for (int it = 0; it < 3; it++) {
      int tt = it * 4 + (tid >> 6);
      int nf = tt >> 1, gk = tt & 1;
      unsigned short v[8];
#pragma unroll
      for (int j = 0; j < 8; j++)
        v[j] = lds[(gk * 16 + hl * 8 + j) * 200 + nf * 32 + ln];
      *(i32x4*)(d2pre + ci * 6144 + tt * 512 + l * 8) = *(i32x4*)v;
    }
    // e1pre: E[g, y, k=lv^2+m] = sum_j psi1[y, lv^2+j] * Da[g, off165 + j*d + m]
    // (off165 = cumulative sum of d'^2 = {0,1,10,35,84} — NOT lv^2!)
    for (int yy = 0; yy < 16; yy++) {
#pragma unroll
      for (int it = 0; it < 4; it++) {
        int idx = it * 256 + tid;          // 0..1023
        int kf = idx >> 9, r2 = idx & 511;
        int ll = r2 >> 3, j = r2 & 7;
        int lnn = ll & 31, hll = ll >> 5;
        int k = kf * 16 + hll * 8 + j;
        unsigned short ov = 0;
        if (k < 25) {
          int lv = (k < 1) ? 0 : (k < 4) ? 1 : (k < 9) ? 2 : (k < 16) ? 3 : 4;
          int d = 2 * lv + 1;
          int m = k - lv * lv;
          int off165 = lv * (4 * lv * lv - 1) / 3;   // {0,1,10,35,84}
          float s = 0.f;
          const float* pr = psi1L + yy * 25 + lv * lv;
          const unsigned short* dr = lds + lnn * 200 + off165 + m;
          for (int j2 = 0; j2 < d; j2++) s += pr[j2] * bf2f(dr[j2 * d]);
          ov = f2bf(s);
        }
        e1pre[((yy * 128 + ci) * 2 + kf) * 512 + ll * 8 + j] = ov;
      }
    }
  } else {
    const int bx2 = blockIdx.x - 128;
    const int n0 = bx2 * 64;
    for (int e = tid; e < 13824; e += 256) lds[e] = 0;
    __syncthreads();
    for (int e = tid; e < 10560; e += 256) {          // 165 rows x 64 cols
      int k = e >> 6, n = e & 63;
      lds[k * 72 + n] = f2bf(ew[k * 4608 + n0 + n]);
    }
    __syncthreads();
#pragma unroll
    for (int it = 0; it < 6; it++) {
      int tb = it * 4 + (tid >> 6);
      int nt2 = tb / 12, kf = tb - nt2 * 12;
      unsigned short v[8];
#pragma unroll
      for (int j = 0; j < 8; j++)
        v[j] = lds[(kf * 16 + hl * 8 + j) * 72 + nt2 * 32 + ln];
      *(i32x4*)(ewpre + (bx2 * 2 + nt2) * 6144 + kf * 512 + l * 8) = *(i32x4*)v;
    }
  }
}

// ---------------- fused MLP (K-folded GEMM1) ----------------
// Grid 512: h = bx&1 (g-half of 64 chunks), y = (bx>>1)&15, btg = bx>>5.
// Wave w -> b-tile bt = btg*4+w (32 batch rows, fixed y). Per chunk (32 g):
// GEMM1: S^T[g][b] = E_y-tile . x-frags (K=32, 2 MFMA); shfl-exchange -> S A-frags;
// GEMM2: O += S . Da (12 MFMA). Staging 14KB/chunk dbuf via global_load_lds.
// Partials out: part[h][y][b][192] bf16 (plain layout).
__global__ __launch_bounds__(256, 2) void fused_mlp_k(
    const float* __restrict__ x,
    const unsigned short* __restrict__ e1pre,
    const unsigned short* __restrict__ d2pre,
    unsigned short* __restrict__ part)
{
  __shared__ __align__(16) unsigned char smem[28672];   // 2 x 14KB (12KB d2 + 2KB E)
  const int tid = threadIdx.x;
  const int w = tid >> 6, l = tid & 63;
  const int hl = l >> 5, ln = l & 31;
  const int h = blockIdx.x & 1;
  const int y = (blockIdx.x >> 1) & 15;
  const int btg = blockIdx.x >> 5;
  const int bt = btg * 4 + w;
  const int c0 = h * 64;

  // x fragments (B-operand of GEMM1): lane ln -> batch b = bt*32+ln, k = hl*8+j (pad 32)
  bf16x8 xf[2];
  {
    const float* xr = x + (bt * 32 + ln) * 25;
#pragma unroll
    for (int kf = 0; kf < 2; kf++) {
      unsigned short v[8];
#pragma unroll
      for (int j = 0; j < 8; j++) {
        int k = kf * 16 + hl * 8 + j;
        v[j] = (k < 25) ? f2bf(xr[k]) : (unsigned short)0;
      }
      xf[kf] = *(bf16x8*)v;
    }
  }

  f32x16 o[6];
#pragma unroll
  for (int nf = 0; nf < 6; nf++) o[nf] = ZERO16;

  const unsigned short* ebase = e1pre + (y * 128) * 1024;

  // prologue: stage chunk c0 -> buffer 0 (14 x 1KB blocks; waves take 4,4,4,2)
#pragma unroll
  for (int i = 0; i < 4; i++) {
    int tb = w * 4 + i;
    if (tb < 14) {
      const unsigned short* g = (tb < 12) ? (d2pre + c0 * 6144 + tb * 512 + l * 8)
                                          : (ebase + (c0 * 2 + (tb - 12)) * 512 + l * 8);
      gl_lds16(g, smem + tb * 1024);
    }
  }

  for (int ci = 0; ci < 64; ci++) {
    __syncthreads();
    const unsigned char* cb = smem + (ci & 1) * 14336;
    if (ci < 63) {
      const unsigned char* nb = smem + ((ci + 1) & 1) * 14336;
      const int c = c0 + ci + 1;
#pragma unroll
      for (int i = 0; i < 4; i++) {
        int tb = w * 4 + i;
        if (tb < 14) {
          const unsigned short* g = (tb < 12) ? (d2pre + c * 6144 + tb * 512 + l * 8)
                                              : (ebase + (c * 2 + (tb - 12)) * 512 + l * 8);
          gl_lds16(g, (void*)(nb + tb * 1024));
        }
      }
    }
    // GEMM1: S^T[g32][b32], K=32
    f32x16 c0a = ZERO16;
    {
      bf16x8 aE0 = *(const bf16x8*)(cb + 12288 + l * 16);
      bf16x8 aE1 = *(const bf16x8*)(cb + 13312 + l * 16);
      c0a = __builtin_amdgcn_mfma_f32_32x32x16_bf16(aE0, xf[0], c0a, 0, 0, 0);
      c0a = __builtin_amdgcn_mfma_f32_32x32x16_bf16(aE1, xf[1], c0a, 0, 0, 0);
    }
    // relu + scale + pack
    unsigned int dw[8];
#pragma unroll
    for (int p = 0; p < 8; p++) {
      float v0 = fmaxf(c0a[2 * p]     * INV_SQRT165, 0.f);
      float v1 = fmaxf(c0a[2 * p + 1] * INV_SQRT165, 0.f);
      dw[p] = pack_bf2(v0, v1);
    }
    // cross-half exchange -> A-frags of S
    unsigned int r1 = __shfl_xor(hl ? dw[0] : dw[2], 32);
    unsigned int r2 = __shfl_xor(hl ? dw[1] : dw[3], 32);
    unsigned int r3 = __shfl_xor(hl ? dw[4] : dw[6], 32);
    unsigned int r4 = __shfl_xor(hl ? dw[5] : dw[7], 32);
    i32x4 a2i0, a2i1;
    if (hl == 0) {
      a2i0 = (i32x4){(int)dw[0], (int)dw[1], (int)r1, (int)r2};
      a2i1 = (i32x4){(int)dw[4], (int)dw[5], (int)r3, (int)r4};
    } else {
      a2i0 = (i32x4){(int)r1, (int)r2, (int)dw[2], (int)dw[3]};
      a2i1 = (i32x4){(int)r3, (int)r4, (int)dw[6], (int)dw[7]};
    }
    bf16x8 a2_0 = __builtin_bit_cast(bf16x8, a2i0);
    bf16x8 a2_1 = __builtin_bit_cast(bf16x8, a2i1);
    // GEMM2 (B from LDS)
#pragma unroll
    for (int gk = 0; gk < 2; gk++) {
      bf16x8 a2 = gk ? a2_1 : a2_0;
#pragma unroll
      for (int nf = 0; nf < 6; nf++) {
        bf16x8 b2 = *(const bf16x8*)(cb + (nf * 2 + gk) * 1024 + l * 16);
        o[nf] = __builtin_amdgcn_mfma_f32_32x32x16_bf16(a2, b2, o[nf], 0, 0, 0);
      }
    }
  }

  // store partials: part[((h*16+y)*2048 + b)*192 + n], raw (scale applied in so3_k)
  unsigned short* pp = part + (size_t)(h * 16 + y) * 2048 * 192 + bt * 32 * 192;
#pragma unroll
  for (int nf = 0; nf < 6; nf++) {
    int n = nf * 32 + ln;
    if (n < 176) {
#pragma unroll
      for (int r = 0; r < 16; r++) {
        int row = (r & 3) + 8 * (r >> 2) + 4 * hl;
        pp[row * 192 + n] = f2bf(o[nf][r]);
      }
    }
  }
}

// ---------------- partial reduce + so3_to_so3 ----------------
// Block per 4 batch elems (512 blocks): sum 2 halves over 16 y, scale -> LDS fp32
// [4][16][180], then Wigner-contract -> harm_out + harmbpre (frag layout for eval).
__global__ __launch_bounds__(256) void so3_k(const unsigned short* __restrict__ part,
                                             const float* __restrict__ psi2,
                                             float* __restrict__ harm_out,
                                             unsigned short* __restrict__ harmbpre) {
  __shared__ float lds[4 * 16 * 180];
  const int tid = threadIdx.x;
  const int b0 = blockIdx.x * 4;
  {
    const int ybl = tid >> 2;              // 0..63: y = ybl&15, bloc = ybl>>4
    const int yy = ybl & 15, bloc = ybl >> 4;
    const int s = tid & 3;
    const unsigned int* r0 = (const unsigned int*)(part + ((size_t)(0 * 16 + yy) * 2048 + b0 + bloc) * 192);
    const unsigned int* r1 = (const unsigned int*)(part + ((size_t)(1 * 16 + yy) * 2048 + b0 + bloc) * 192);
    float* dst = lds + (bloc * 16 + yy) * 180;
#pragma unroll
    for (int t = 0; t < 22; t++) {         // dwords 0..87 cover n 0..175
      int d = s * 22 + t;
      if (d < 88) {
        unsigned int u0 = r0[d], u1 = r1[d];
        int n0 = d * 2;
        float lo = bf2f((unsigned short)(u0 & 0xFFFF)) + bf2f((unsigned short)(u1 & 0xFFFF));
        float hi = bf2f((unsigned short)(u0 >> 16))    + bf2f((unsigned short)(u1 >> 16));
        dst[n0]     = lo * FINAL_SCALE;
        dst[n0 + 1] = hi * FINAL_SCALE;
      }
    }
  }
  __syncthreads();
  for (int jj = tid; jj < 768; jj += 256) {
    int e = (jj * 683) >> 17;              // jj / 192
    int i = jj - e * 192;
    int bb = b0 + e;
    unsigned short* hb = harmbpre + (((bb >> 5) * 12 + (i >> 4)) << 9)
                       + ((i >> 3) & 1) * 256 + (bb & 31) * 8 + (i & 7);
    if (i < 165) {
      const float* row0 = lds + e * (16 * 180);
      int lv, rel; decode_i(i, lv, rel);
      int d = 2 * lv + 1;
      int off = i - rel;
      int v = divq(rel, lv), m = rel - v * d;
      float s = 0.f;
      for (int ch = 0; ch < 16; ch++) {
        const float* rw = row0 + ch * 180 + off;
        const float* p2 = psi2 + ch * 165 + off;
        for (int u = 0; u < d; u++) s += rw[u * d + m] * p2[u * d + v];
      }
      s *= 0.25f * rsqrtf((float)d);
      harm_out[bb * 165 + i] = s;
      *hb = f2bf(s);
    } else {
      *hb = 0;
    }
  }
}

// ---------------- eval GEMM: logits = harm . ew  (2048 x 4608, K=192) ----------------
// One wave per block (grid 24 x 64) for latency hiding.
__global__ __launch_bounds__(64) void eval_k(
    const unsigned short* __restrict__ harmbpre,
    const unsigned short* __restrict__ ewpre,
    float* __restrict__ logits)
{
  const int l = threadIdx.x;
  const int hl = l >> 5, ln = l & 31;
  const int mt = blockIdx.y;
  const int n0 = blockIdx.x * 192;

  bf16x8 a[12];
  const short* ap = (const short*)harmbpre + mt * 6144 + l * 8;
#pragma unroll
  for (int kf = 0; kf < 12; kf++) a[kf] = *(const bf16x8*)(ap + kf * 512);

  f32x16 acc[6];
#pragma unroll
  for (int nf = 0; nf < 6; nf++) acc[nf] = ZERO16;

  const short* bp = (const short*)ewpre + (blockIdx.x * 6) * 6144 + l * 8;
#pragma unroll
  for (int kf = 0; kf < 12; kf++) {
#pragma unroll
    for (int nf = 0; nf < 6; nf++) {
      bf16x8 b = *(const bf16x8*)(bp + nf * 6144 + kf * 512);
      acc[nf] = __builtin_amdgcn_mfma_f32_32x32x16_bf16(a[kf], b, acc[nf], 0, 0, 0);
    }
  }
#pragma unroll
  for (int nf = 0; nf < 6; nf++) {
    const int col = n0 + nf * 32 + ln;
#pragma unroll
    for (int r = 0; r < 16; r++) {
      int row = (r & 3) + 8 * (r >> 2) + 4 * hl;
      logits[(mt * 32 + row) * 4608 + col] = acc[nf][r];
    }
  }
}

// ---------------- fifth prob from row-0 logits ----------------
__global__ __launch_bounds__(256) void fifth_k(const float* __restrict__ logit0,
                                               float* __restrict__ fifth) {
  __shared__ float buf[4608];
  __shared__ float sm[4], ss[4];
  __shared__ float wv[4]; __shared__ int wi[4];
  __shared__ float gbest;
  const int tid = threadIdx.x;
  const int l = tid & 63, w = tid >> 6;
  float v[18];
  float mx = -3.4e38f;
#pragma unroll
  for (int i = 0; i < 18; i++) {
    v[i] = logit0[i * 256 + tid];
    buf[i * 256 + tid] = v[i];
    mx = fmaxf(mx, v[i]);
  }
#pragma unroll
  for (int off = 32; off >= 1; off >>= 1) mx = fmaxf(mx, __shfl_xor(mx, off));
  if (l == 0) sm[w] = mx;
  __syncthreads();
  mx = fmaxf(fmaxf(sm[0], sm[1]), fmaxf(sm[2], sm[3]));
  float s = 0.f;
#pragma unroll
  for (int i = 0; i < 18; i++) { v[i] = __expf(v[i] - mx); s += v[i]; }
#pragma unroll
  for (int off = 32; off >= 1; off >>= 1) s += __shfl_xor(s, off);
  if (l == 0) ss[w] = s;
  __syncthreads();
  s = ss[0] + ss[1] + ss[2] + ss[3];
  float inv = 1.f / s;

  float ff = 0.f;
  for (int it = 0; it < 5; it++) {
    float bm = -3.4e38f; int bi = 0;
    for (int i = tid; i < 4608; i += 256) {
      float xx = buf[i];
      if (xx > bm) { bm = xx; bi = i; }
    }
    for (int off = 32; off >= 1; off >>= 1) {
      float ov = __shfl_xor(bm, off); int oi = __shfl_xor(bi, off);
      if (ov > bm) { bm = ov; bi = oi; }
    }
    if (l == 0) { wv[w] = bm; wi[w] = bi; }
    __syncthreads();
    if (tid == 0) {
      float B = wv[0]; int I = wi[0];
      for (int k = 1; k < 4; k++) if (wv[k] > B) { B = wv[k]; I = wi[k]; }
      gbest = B;
      buf[I] = -3.4e38f;
    }
    __syncthreads();
    ff = gbest;
    __syncthreads();
  }
  if (tid == 0) *fifth = __expf(ff - mx) * inv;
}

// ---------------- fused softmax + threshold ----------------
__global__ __launch_bounds__(256) void smthresh_k(float* __restrict__ probs,
                                                  const float* __restrict__ fifth) {
  float* p = probs + (size_t)blockIdx.x * 4608;
  const int tid = threadIdx.x;
  const int l = tid & 63, w = tid >> 6;
  __shared__ float sm[4], ss[4];
  float v[18];
  float mx = -3.4e38f;
#pragma unroll
  for (int i = 0; i < 18; i++) { v[i] = p[i * 256 + tid]; mx = fmaxf(mx, v[i]); }
#pragma unroll
  for (int off = 32; off >= 1; off >>= 1) mx = fmaxf(mx, __shfl_xor(mx, off));
  if (l == 0) sm[w] = mx;
  __syncthreads();
  mx = fmaxf(fmaxf(sm[0], sm[1]), fmaxf(sm[2], sm[3]));
  float s = 0.f;
#pragma unroll
  for (int i = 0; i < 18; i++) { v[i] = __expf(v[i] - mx); s += v[i]; }
#pragma unroll
  for (int off = 32; off >= 1; off >>= 1) s += __shfl_xor(s, off);
  if (l == 0) ss[w] = s;
  __syncthreads();
  s = ss[0] + ss[1] + ss[2] + ss[3];
  float inv = 1.f / s;
  float t = *fifth;
#pragma unroll
  for (int i = 0; i < 18; i++) {
    float pv = v[i] * inv;
    p[i * 256 + tid] = (pv < t) ? 0.f : pv;
  }
}

extern "C" void kernel_launch(void* const* d_in, const int* in_sizes, int n_in,
                              void* d_out, int out_size, void* d_ws, size_t ws_size,
                              hipStream_t stream) {
  const float* x     = (const float*)d_in[0];
  const float* w_s2  = (const float*)d_in[1];
  const float* Y     = (const float*)d_in[2];
  const float* w_so3 = (const float*)d_in[3];
  const float* Dk    = (const float*)d_in[4];
  const float* Da    = (const float*)d_in[5];
  const float* ew    = (const float*)d_in[6];

  float* out = (float*)d_out;
  float* harm_out = out;                 // 2048*165
  float* probs    = out + 337920;        // 2048*4608 (partials -> logits -> probs)
  unsigned short* part = (unsigned short*)probs;   // 25.2 MB bf16 partials

  char* ws = (char*)d_ws;
  float* psi1  = (float*)(ws + 0);                         // 1,600 B
  float* psi2  = (float*)(ws + 1600);                      // 10,560 B
  float* fifth = (float*)(ws + 12160);                     // 4 B
  unsigned short* e1pre    = (unsigned short*)(ws + 12288);      // 4,194,304 B
  unsigned short* d2pre    = (unsigned short*)(ws + 4206592);    // 1,572,864 B
  unsigned short* ewpre    = (unsigned short*)(ws + 5779456);    // 1,769,472 B
  unsigned short* harmbpre = (unsigned short*)(ws + 7548928);    // 786,432 B (~8.3 MB)

  psi_k <<<13,  256, 0, stream>>>(Y, w_s2, Dk, w_so3, psi1, psi2);
  prep_k<<<200, 256, 0, stream>>>(Da, ew, psi1, e1pre, d2pre, ewpre);
  fused_mlp_k<<<512, 256, 0, stream>>>(x, e1pre, d2pre, part);
  so3_k<<<512, 256, 0, stream>>>(part, psi2, harm_out, harmbpre);
  eval_k<<<dim3(24, 64), 64, 0, stream>>>(harmbpre, ewpre, probs);
  fifth_k<<<1, 256, 0, stream>>>(probs, fifth);
  smthresh_k<<<2048, 256, 0, stream>>>(probs, fifth);
}